// Round 1
// baseline (58.609 us; speedup 1.0000x reference)
//
#include <hip/hip_runtime.h>
#include <math.h>

#define LSEP_N 512
#define LSEP_C 512

__inline__ __device__ float wave_reduce_sum(float v) {
    // wave64 butterfly
    #pragma unroll
    for (int o = 32; o > 0; o >>= 1) v += __shfl_down(v, o, 64);
    return v;
}

__inline__ __device__ float block_reduce_sum(float v, float* smem /* >= 8 floats */) {
    const int lane = threadIdx.x & 63;
    const int wid  = threadIdx.x >> 6;
    const int nw   = blockDim.x >> 6;
    v = wave_reduce_sum(v);
    if (lane == 0) smem[wid] = v;
    __syncthreads();
    float r = 0.f;
    if (wid == 0) {
        r = (lane < nw) ? smem[lane] : 0.f;
        r = wave_reduce_sum(r);
    }
    return r; // valid in wave 0 lane 0
}

// One block per row: s = (sum_{y==0} exp(x)) * (sum_{y==1} exp(-x));
// row_out[row] = log1p(s)
__global__ void lsep_row_kernel(const int* __restrict__ y_true,
                                const float* __restrict__ y_pred,
                                float* __restrict__ row_out) {
    const int row = blockIdx.x;
    const int* yt = y_true + (size_t)row * LSEP_C;
    const float* yp = y_pred + (size_t)row * LSEP_C;

    float sneg = 0.f, spos = 0.f;
    for (int c = threadIdx.x; c < LSEP_C; c += blockDim.x) {
        const float x = yp[c];
        const int t = yt[c];
        const float e = expf(x);
        if (t == 0) sneg += e;
        else if (t == 1) spos += 1.0f / e;  // exp(-x)
    }

    __shared__ float sm_a[8];
    __shared__ float sm_b[8];

    // two block reductions (separate shared buffers, one barrier pair each)
    const int lane = threadIdx.x & 63;
    const int wid  = threadIdx.x >> 6;
    const int nw   = blockDim.x >> 6;

    sneg = wave_reduce_sum(sneg);
    spos = wave_reduce_sum(spos);
    if (lane == 0) { sm_a[wid] = sneg; sm_b[wid] = spos; }
    __syncthreads();
    if (wid == 0) {
        float a = (lane < nw) ? sm_a[lane] : 0.f;
        float b = (lane < nw) ? sm_b[lane] : 0.f;
        a = wave_reduce_sum(a);
        b = wave_reduce_sum(b);
        if (lane == 0) row_out[row] = log1pf(a * b);
    }
}

// Single block: mean of row values
__global__ void lsep_final_kernel(const float* __restrict__ row_vals,
                                  float* __restrict__ out) {
    float v = 0.f;
    for (int i = threadIdx.x; i < LSEP_N; i += blockDim.x) v += row_vals[i];
    __shared__ float sm[8];
    const float total = block_reduce_sum(v, sm);
    if (threadIdx.x == 0) out[0] = total / (float)LSEP_N;
}

extern "C" void kernel_launch(void* const* d_in, const int* in_sizes, int n_in,
                              void* d_out, int out_size, void* d_ws, size_t ws_size,
                              hipStream_t stream) {
    const int* y_true = (const int*)d_in[0];
    const float* y_pred = (const float*)d_in[1];
    float* out = (float*)d_out;
    float* row_vals = (float*)d_ws;  // needs 512 * 4 B = 2 KB

    lsep_row_kernel<<<LSEP_N, 256, 0, stream>>>(y_true, y_pred, row_vals);
    lsep_final_kernel<<<1, 256, 0, stream>>>(row_vals, out);
}